// Round 1
// baseline (456.403 us; speedup 1.0000x reference)
//
#include <hip/hip_runtime.h>
#include <hip/hip_bf16.h>
#include <stdint.h>

#define NCAT 32
#define DIN  1536
#define DMID 1024
#define NB   128
#define TT   32

#define BM 128
#define BN 128
#define BK 32
#define LDA 40   // ushort stride for A tile rows (padded, keeps 16B align, spreads banks)
#define MAXG 56  // max groups: sum ceil(n_c/4) <= 128/4 + 32*3/4 = 56

typedef __attribute__((ext_vector_type(8))) short short8;
typedef __attribute__((ext_vector_type(4))) float f32x4;

static __device__ __forceinline__ unsigned int pk2bf(float lo, float hi) {
  unsigned short a = __builtin_bit_cast(unsigned short, __float2bfloat16(lo));
  unsigned short b = __builtin_bit_cast(unsigned short, __float2bfloat16(hi));
  return ((unsigned int)b << 16) | (unsigned int)a;
}

// ws int layout: [0..127] batch_list sorted by category; [128] num_groups;
// [132 + 4g .. ] = {cat, start, cnt, pad}. hidden bf16 at byte offset 8192.
__global__ void build_groups(const int* __restrict__ cat_ids, int* __restrict__ wsi) {
  __shared__ int cats[NB];
  __shared__ int cnt[NCAT];
  __shared__ int off[NCAT];
  int t = threadIdx.x; // blockDim = 128
  cats[t] = cat_ids[t];
  __syncthreads();
  if (t < NCAT) {
    int n = 0;
    for (int b = 0; b < NB; b++) n += (cats[b] == t);
    cnt[t] = n;
  }
  __syncthreads();
  if (t == 0) {
    int acc = 0;
    for (int c = 0; c < NCAT; c++) { off[c] = acc; acc += cnt[c]; }
  }
  __syncthreads();
  if (t < NCAT) {
    int o = off[t];
    for (int b = 0; b < NB; b++)
      if (cats[b] == t) wsi[o++] = b;
  }
  if (t == 0) {
    int g = 0;
    for (int c = 0; c < NCAT; c++) {
      int n = cnt[c], o = off[c];
      for (int j = 0; j < n; j += 4) {
        wsi[132 + g * 4 + 0] = c;
        wsi[132 + g * 4 + 1] = o + j;
        wsi[132 + g * 4 + 2] = (n - j) < 4 ? (n - j) : 4;
        g++;
      }
    }
    wsi[128] = g;
  }
}

// LAYER 1: Ain = x (fp32, rows [batch*32+t][K=1536]), Out = hidden bf16 [4096][1024], relu
// LAYER 2: Ain = hidden (bf16 [4096][1024]), Out = final fp32 [4096][1024]
template <int LAYER>
__global__ __launch_bounds__(256, 2)
void mlp_gemm(const void* __restrict__ Ain, const float* __restrict__ W,
              const float* __restrict__ bias, const int* __restrict__ wsi,
              void* __restrict__ Out, int K) {
  int gid = blockIdx.y;
  if (gid >= wsi[128]) return;
  const int cat   = wsi[132 + gid * 4 + 0];
  const int start = wsi[132 + gid * 4 + 1];
  const int cnt   = wsi[132 + gid * 4 + 2];
  const int n0    = blockIdx.x * BN;

  __shared__ unsigned short As[BM * LDA];      // 10240 B, row-major [row][k] bf16
  __shared__ unsigned short Bs[4 * 128 * 8];   // 8192 B, blocks [kc][n^swz][8k] bf16

  const int tid  = threadIdx.x;
  const int lane = tid & 63;
  const int w    = tid >> 6;   // wave id 0..3

  // ---- A staging assignment: thread -> (row = tid>>1, khalf = (tid&1)*16)
  const int arow  = tid >> 1;
  const int khalf = (tid & 1) * 16;
  const int lb    = arow >> 5;
  const int tok   = arow & 31;
  const int lbc   = lb < (cnt - 1) ? lb : (cnt - 1);
  const int batch = wsi[start + lbc];
  const long grow = (long)(batch * TT + tok);

  // ---- B staging assignment: thread -> kc = w (k rows w*8..w*8+7), cols bn, bn+1
  const int bn = 2 * lane;
  const float* Wg = W + (size_t)cat * (size_t)K * 1024 + n0;

  f32x4 acc[4][4];
#pragma unroll
  for (int i = 0; i < 4; i++)
#pragma unroll
    for (int j = 0; j < 4; j++) acc[i][j] = (f32x4){0.f, 0.f, 0.f, 0.f};

  const int wm = (w >> 1) * 64;
  const int wn = (w & 1) * 64;
  const int kg = lane >> 4;       // 0..3
  const int c16 = lane & 15;

  for (int k0 = 0; k0 < K; k0 += BK) {
    // ---------- global loads (before barrier, overlap with prior compute) ----------
    uint4 aw0, aw1;
    if constexpr (LAYER == 1) {
      const float* ap = (const float*)Ain + grow * (long)K + k0 + khalf;
      float4 a0 = *(const float4*)(ap + 0);
      float4 a1 = *(const float4*)(ap + 4);
      float4 a2 = *(const float4*)(ap + 8);
      float4 a3 = *(const float4*)(ap + 12);
      aw0 = make_uint4(pk2bf(a0.x, a0.y), pk2bf(a0.z, a0.w),
                       pk2bf(a1.x, a1.y), pk2bf(a1.z, a1.w));
      aw1 = make_uint4(pk2bf(a2.x, a2.y), pk2bf(a2.z, a2.w),
                       pk2bf(a3.x, a3.y), pk2bf(a3.z, a3.w));
    } else {
      const uint4* ap = (const uint4*)((const unsigned short*)Ain + grow * (long)K + k0 + khalf);
      aw0 = ap[0];
      aw1 = ap[1];
    }
    float2 bv[8];
    {
      const float* bp = Wg + (size_t)(k0 + w * 8) * 1024 + bn;
#pragma unroll
      for (int r = 0; r < 8; r++) bv[r] = *(const float2*)(bp + (size_t)r * 1024);
    }
    uint4 bw0 = make_uint4(pk2bf(bv[0].x, bv[1].x), pk2bf(bv[2].x, bv[3].x),
                           pk2bf(bv[4].x, bv[5].x), pk2bf(bv[6].x, bv[7].x));
    uint4 bw1 = make_uint4(pk2bf(bv[0].y, bv[1].y), pk2bf(bv[2].y, bv[3].y),
                           pk2bf(bv[4].y, bv[5].y), pk2bf(bv[6].y, bv[7].y));

    __syncthreads();  // previous iteration's LDS reads done

    // ---------- LDS writes ----------
    *(uint4*)&As[arow * LDA + khalf]     = aw0;
    *(uint4*)&As[arow * LDA + khalf + 8] = aw1;
    {
      int nA = bn, nB = bn + 1;
      int sA = (w * 128 + (nA ^ ((nA >> 3) & 1))) * 8;  // swizzle spreads banks
      int sB = (w * 128 + (nB ^ ((nB >> 3) & 1))) * 8;
      *(uint4*)&Bs[sA] = bw0;
      *(uint4*)&Bs[sB] = bw1;
    }
    __syncthreads();

    // ---------- fragments + MFMA ----------
    short8 afrag[4], bfrag[4];
#pragma unroll
    for (int i = 0; i < 4; i++)
      afrag[i] = *(const short8*)&As[(wm + i * 16 + c16) * LDA + kg * 8];
#pragma unroll
    for (int j = 0; j < 4; j++) {
      int n = wn + j * 16 + c16;
      int slot = (kg * 128 + (n ^ ((n >> 3) & 1))) * 8;
      bfrag[j] = *(const short8*)&Bs[slot];
    }
#pragma unroll
    for (int i = 0; i < 4; i++)
#pragma unroll
      for (int j = 0; j < 4; j++)
        acc[i][j] = __builtin_amdgcn_mfma_f32_16x16x32_bf16(afrag[i], bfrag[j], acc[i][j], 0, 0, 0);
  }

  // ---------- epilogue ----------
  const int rquad = (lane >> 4) * 4;
#pragma unroll
  for (int i = 0; i < 4; i++) {
#pragma unroll
    for (int j = 0; j < 4; j++) {
      int gcol = n0 + wn + j * 16 + c16;
      float bb = bias[cat * 1024 + gcol];
#pragma unroll
      for (int r = 0; r < 4; r++) {
        int lrow = wm + i * 16 + rquad + r;
        int lb2 = lrow >> 5;
        if (lb2 < cnt) {
          int b2 = wsi[start + lb2];
          long orow = (long)(b2 * TT + (lrow & 31));
          float v = acc[i][j][r] + bb;
          if constexpr (LAYER == 1) {
            v = fmaxf(v, 0.f);
            ((unsigned short*)Out)[orow * DMID + gcol] =
                __builtin_bit_cast(unsigned short, __float2bfloat16(v));
          } else {
            ((float*)Out)[orow * 1024 + gcol] = v;
          }
        }
      }
    }
  }
}

extern "C" void kernel_launch(void* const* d_in, const int* in_sizes, int n_in,
                              void* d_out, int out_size, void* d_ws, size_t ws_size,
                              hipStream_t stream) {
  const float* x       = (const float*)d_in[0];
  const int*   cat_ids = (const int*)d_in[1];
  const float* W1      = (const float*)d_in[2];
  const float* b1      = (const float*)d_in[3];
  const float* W2      = (const float*)d_in[4];
  const float* b2      = (const float*)d_in[5];
  float* out = (float*)d_out;

  int* wsi = (int*)d_ws;
  unsigned short* hidden = (unsigned short*)((char*)d_ws + 8192);

  build_groups<<<dim3(1), dim3(128), 0, stream>>>(cat_ids, wsi);
  mlp_gemm<1><<<dim3(DMID / BN, MAXG), dim3(256), 0, stream>>>(
      (const void*)x, W1, b1, wsi, (void*)hidden, DIN);
  mlp_gemm<2><<<dim3(1024 / BN, MAXG), dim3(256), 0, stream>>>(
      (const void*)hidden, W2, b2, wsi, (void*)out, DMID);
}

// Round 2
// 444.758 us; speedup vs baseline: 1.0262x; 1.0262x over previous
//
#include <hip/hip_runtime.h>
#include <hip/hip_bf16.h>
#include <stdint.h>

#define NCAT 32
#define DIN  1536
#define DMID 1024
#define NB   128
#define TT   32

#define BM 128
#define BN 64
#define BK 32
#define LDA 40   // ushort stride for A tile rows (padded, keeps 16B align, spreads banks)
#define MAXG 56  // max groups: sum ceil(n_c/4) <= 56

typedef __attribute__((ext_vector_type(8))) short short8;
typedef __attribute__((ext_vector_type(4))) float f32x4;

static __device__ __forceinline__ unsigned int pk2bf(float lo, float hi) {
  unsigned short a = __builtin_bit_cast(unsigned short, __float2bfloat16(lo));
  unsigned short b = __builtin_bit_cast(unsigned short, __float2bfloat16(hi));
  return ((unsigned int)b << 16) | (unsigned int)a;
}

// ws int layout: [0..127] batch_list sorted by category; [128] num_groups;
// [132 + 4g ..] = {cat, start, cnt, pad}. hidden bf16 at byte offset 8192.
__global__ void build_groups(const int* __restrict__ cat_ids, int* __restrict__ wsi) {
  __shared__ int cats[NB];
  __shared__ int cnt[NCAT];
  __shared__ int off[NCAT];
  int t = threadIdx.x; // blockDim = 128
  cats[t] = cat_ids[t];
  __syncthreads();
  if (t < NCAT) {
    int n = 0;
    for (int b = 0; b < NB; b++) n += (cats[b] == t);
    cnt[t] = n;
  }
  __syncthreads();
  if (t == 0) {
    int acc = 0;
    for (int c = 0; c < NCAT; c++) { off[c] = acc; acc += cnt[c]; }
  }
  __syncthreads();
  if (t < NCAT) {
    int o = off[t];
    for (int b = 0; b < NB; b++)
      if (cats[b] == t) wsi[o++] = b;
  }
  if (t == 0) {
    int g = 0;
    for (int c = 0; c < NCAT; c++) {
      int n = cnt[c], o = off[c];
      for (int j = 0; j < n; j += 4) {
        wsi[132 + g * 4 + 0] = c;
        wsi[132 + g * 4 + 1] = o + j;
        wsi[132 + g * 4 + 2] = (n - j) < 4 ? (n - j) : 4;
        g++;
      }
    }
    wsi[128] = g;
  }
}

// LAYER 1: Ain = x (fp32, rows [batch*32+t][K=1536]), Out = hidden bf16 [4096][1024], relu
// LAYER 2: Ain = hidden (bf16 [4096][1024]), Out = final fp32 [4096][1024]
template <int LAYER>
__global__ __launch_bounds__(256)
void mlp_gemm(const void* __restrict__ Ain, const float* __restrict__ W,
              const float* __restrict__ bias, const int* __restrict__ wsi,
              void* __restrict__ Out, int K) {
  int gid = blockIdx.y;
  if (gid >= wsi[128]) return;
  const int cat   = wsi[132 + gid * 4 + 0];
  const int start = wsi[132 + gid * 4 + 1];
  const int cnt   = wsi[132 + gid * 4 + 2];
  const int n0    = blockIdx.x * BN;

  __shared__ unsigned short As[BM * LDA];    // 10240 B, row-major [row][k] bf16
  __shared__ unsigned short Bs[4 * BN * 8];  // 4096 B, chunked [kc][n][8k] bf16

  const int tid  = threadIdx.x;
  const int lane = tid & 63;
  const int w    = tid >> 6;   // wave id 0..3

  // ---- A staging: thread -> (row = tid>>1, khalf = (tid&1)*16)
  const int arow  = tid >> 1;
  const int khalf = (tid & 1) * 16;
  const int lb    = arow >> 5;
  const int tok   = arow & 31;
  const int lbc   = lb < (cnt - 1) ? lb : (cnt - 1);
  const int batch = wsi[start + lbc];
  const long grow = (long)(batch * TT + tok);

  // ---- B staging: thread -> kc = w (k rows w*8..w*8+7), col = lane
  const float* Wcol = W + (size_t)cat * (size_t)K * 1024 + n0 + lane;

  f32x4 acc[4][2];
#pragma unroll
  for (int i = 0; i < 4; i++)
#pragma unroll
    for (int j = 0; j < 2; j++) acc[i][j] = (f32x4){0.f, 0.f, 0.f, 0.f};

  const int wm  = (w >> 1) * 64;
  const int wn  = (w & 1) * 32;
  const int kg  = lane >> 4;    // 0..3
  const int c16 = lane & 15;

  auto load_tile = [&](int k0, float4 ar[4], uint4& ah0, uint4& ah1, float br[8]) {
    if constexpr (LAYER == 1) {
      const float* ap = (const float*)Ain + grow * (long)K + k0 + khalf;
      ar[0] = *(const float4*)(ap + 0);
      ar[1] = *(const float4*)(ap + 4);
      ar[2] = *(const float4*)(ap + 8);
      ar[3] = *(const float4*)(ap + 12);
    } else {
      const uint4* ap = (const uint4*)((const unsigned short*)Ain + grow * (long)K + k0 + khalf);
      ah0 = ap[0];
      ah1 = ap[1];
    }
    const float* bp = Wcol + (size_t)(k0 + w * 8) * 1024;
#pragma unroll
    for (int r = 0; r < 8; r++) br[r] = bp[(size_t)r * 1024];
  };

  auto store_tile = [&](const float4 ar[4], const uint4& ah0, const uint4& ah1,
                        const float br[8]) {
    if constexpr (LAYER == 1) {
      uint4 aw0 = make_uint4(pk2bf(ar[0].x, ar[0].y), pk2bf(ar[0].z, ar[0].w),
                             pk2bf(ar[1].x, ar[1].y), pk2bf(ar[1].z, ar[1].w));
      uint4 aw1 = make_uint4(pk2bf(ar[2].x, ar[2].y), pk2bf(ar[2].z, ar[2].w),
                             pk2bf(ar[3].x, ar[3].y), pk2bf(ar[3].z, ar[3].w));
      *(uint4*)&As[arow * LDA + khalf]     = aw0;
      *(uint4*)&As[arow * LDA + khalf + 8] = aw1;
    } else {
      *(uint4*)&As[arow * LDA + khalf]     = ah0;
      *(uint4*)&As[arow * LDA + khalf + 8] = ah1;
    }
    uint4 bw = make_uint4(pk2bf(br[0], br[1]), pk2bf(br[2], br[3]),
                          pk2bf(br[4], br[5]), pk2bf(br[6], br[7]));
    *(uint4*)&Bs[(w * BN + lane) * 8] = bw;
  };

  float4 arC[4]; uint4 ah0C, ah1C; float brC[8];
  load_tile(0, arC, ah0C, ah1C, brC);

  for (int k0 = 0; k0 < K; k0 += BK) {
    __syncthreads();                 // previous iteration's LDS reads done
    store_tile(arC, ah0C, ah1C, brC);
    __syncthreads();

    // issue next tile's global loads before compute (latency overlapped)
    float4 arN[4]; uint4 ah0N, ah1N; float brN[8];
    if (k0 + BK < K) load_tile(k0 + BK, arN, ah0N, ah1N, brN);

    short8 afrag[4], bfrag[2];
#pragma unroll
    for (int i = 0; i < 4; i++)
      afrag[i] = *(const short8*)&As[(wm + i * 16 + c16) * LDA + kg * 8];
#pragma unroll
    for (int j = 0; j < 2; j++)
      bfrag[j] = *(const short8*)&Bs[(kg * BN + wn + j * 16 + c16) * 8];
#pragma unroll
    for (int i = 0; i < 4; i++)
#pragma unroll
      for (int j = 0; j < 2; j++)
        acc[i][j] = __builtin_amdgcn_mfma_f32_16x16x32_bf16(afrag[i], bfrag[j], acc[i][j], 0, 0, 0);

#pragma unroll
    for (int i = 0; i < 4; i++) arC[i] = arN[i];
    ah0C = ah0N; ah1C = ah1N;
#pragma unroll
    for (int r = 0; r < 8; r++) brC[r] = brN[r];
  }

  // ---------- epilogue ----------
  const int rquad = (lane >> 4) * 4;
#pragma unroll
  for (int i = 0; i < 4; i++) {
#pragma unroll
    for (int j = 0; j < 2; j++) {
      int gcol = n0 + wn + j * 16 + c16;
      float bb = bias[cat * 1024 + gcol];
#pragma unroll
      for (int r = 0; r < 4; r++) {
        int lrow = wm + i * 16 + rquad + r;
        int lb2 = lrow >> 5;
        if (lb2 < cnt) {
          int b2 = wsi[start + lb2];
          long orow = (long)(b2 * TT + (lrow & 31));
          float v = acc[i][j][r] + bb;
          if constexpr (LAYER == 1) {
            v = fmaxf(v, 0.f);
            ((unsigned short*)Out)[orow * DMID + gcol] =
                __builtin_bit_cast(unsigned short, __float2bfloat16(v));
          } else {
            ((float*)Out)[orow * 1024 + gcol] = v;
          }
        }
      }
    }
  }
}

extern "C" void kernel_launch(void* const* d_in, const int* in_sizes, int n_in,
                              void* d_out, int out_size, void* d_ws, size_t ws_size,
                              hipStream_t stream) {
  const float* x       = (const float*)d_in[0];
  const int*   cat_ids = (const int*)d_in[1];
  const float* W1      = (const float*)d_in[2];
  const float* b1      = (const float*)d_in[3];
  const float* W2      = (const float*)d_in[4];
  const float* b2      = (const float*)d_in[5];
  float* out = (float*)d_out;

  int* wsi = (int*)d_ws;
  unsigned short* hidden = (unsigned short*)((char*)d_ws + 8192);

  build_groups<<<dim3(1), dim3(128), 0, stream>>>(cat_ids, wsi);
  mlp_gemm<1><<<dim3(1024 / BN, MAXG), dim3(256), 0, stream>>>(
      (const void*)x, W1, b1, wsi, (void*)hidden, DIN);
  mlp_gemm<2><<<dim3(1024 / BN, MAXG), dim3(256), 0, stream>>>(
      (const void*)hidden, W2, b2, wsi, (void*)out, DMID);
}